// Round 6
// baseline (282.334 us; speedup 1.0000x reference)
//
#include <hip/hip_runtime.h>
#include <hip/hip_bf16.h>
#include <math.h>

#define B_ 2
#define L_ 1024
#define D_ 1024
#define DI_ 2048
#define K_ 4
#define N_ 16
#define R_ 64
#define BL_ (B_ * L_)
#define EPS_ 1e-5f

#define IDX4(l) ((l) + (((l) >> 6) << 2))

typedef __attribute__((ext_vector_type(8))) short short8;
typedef __attribute__((ext_vector_type(4))) float f32x4;

__device__ inline unsigned short f2bf(float f) {
    unsigned u = __float_as_uint(f);
    unsigned r = (u + 0x7fffu + ((u >> 16) & 1u)) >> 16;
    return (unsigned short)r;
}
__device__ inline float bf2f(unsigned short s) {
    return __uint_as_float(((unsigned)s) << 16);
}
__device__ inline float fast_silu(float z) {
    return z * __builtin_amdgcn_rcpf(1.f + __expf(-z));
}
#if __has_builtin(__builtin_amdgcn_exp2f)
__device__ inline float fexp2(float x) { return __builtin_amdgcn_exp2f(x); }
#else
__device__ inline float fexp2(float x) { return exp2f(x); }
#endif
__device__ inline void gl_lds16(const void* g, void* l) {
    __builtin_amdgcn_global_load_lds(
        (const __attribute__((address_space(1))) void*)g,
        (__attribute__((address_space(3))) void*)l, 16, 0, 0);
}

// DPP row_shr; row = 16 lanes. Sum lands in lane (n==15) of each 16-lane row. [verified R5/R6]
template <int CTRL>
__device__ inline float dpp_shr(float x) {
    return __int_as_float(__builtin_amdgcn_update_dpp(
        0, __float_as_int(x), CTRL, 0xf, 0xf, true));
}
__device__ inline float row16_sum(float p) {
    p += dpp_shr<0x111>(p);
    p += dpp_shr<0x112>(p);
    p += dpp_shr<0x114>(p);
    p += dpp_shr<0x118>(p);
    return p;
}

// ---------------- LayerNorm -> bf16 ----------------
__global__ void ln_kernel(const float* __restrict__ x, const float* __restrict__ w,
                          const float* __restrict__ b, unsigned short* __restrict__ hb) {
    int row = blockIdx.x;
    const float* xr = x + (size_t)row * D_;
    float4 v = ((const float4*)xr)[threadIdx.x];

    __shared__ float red[4];
    float s = v.x + v.y + v.z + v.w;
    for (int off = 1; off < 64; off <<= 1) s += __shfl_xor(s, off, 64);
    if ((threadIdx.x & 63) == 0) red[threadIdx.x >> 6] = s;
    __syncthreads();
    float mu = (red[0] + red[1] + red[2] + red[3]) * (1.0f / D_);
    __syncthreads();
    float cx = v.x - mu, cy = v.y - mu, cz = v.z - mu, cw = v.w - mu;
    float sq = cx*cx + cy*cy + cz*cz + cw*cw;
    for (int off = 1; off < 64; off <<= 1) sq += __shfl_xor(sq, off, 64);
    if ((threadIdx.x & 63) == 0) red[threadIdx.x >> 6] = sq;
    __syncthreads();
    float var = (red[0] + red[1] + red[2] + red[3]) * (1.0f / D_);
    float rstd = rsqrtf(var + EPS_);

    float4 wv = ((const float4*)w)[threadIdx.x];
    float4 bv = ((const float4*)b)[threadIdx.x];
    ushort4 o;
    o.x = f2bf(cx * rstd * wv.x + bv.x);
    o.y = f2bf(cy * rstd * wv.y + bv.y);
    o.z = f2bf(cz * rstd * wv.z + bv.z);
    o.w = f2bf(cw * rstd * wv.w + bv.w);
    ((ushort4*)(hb + (size_t)row * D_))[threadIdx.x] = o;
}

// ---------------- Merged transpose+cast of all three weights ----------------
__global__ void transpose_cast_all(const float* __restrict__ W_in, const float* __restrict__ W_x,
                                   const float* __restrict__ W_out,
                                   unsigned short* __restrict__ WinT, unsigned short* __restrict__ WxT,
                                   unsigned short* __restrict__ WoutT) {
    int bid = blockIdx.x;
    const float* W; unsigned short* WT; int K, N, bx, by;
    if (bid < 4096)      { W = W_in;  WT = WinT;  K = 1024; N = 4096; bx = bid & 127; by = bid >> 7; }
    else if (bid < 4288) { int id = bid - 4096; W = W_x;  WT = WxT;  K = DI_; N = 96;   bx = id % 3;  by = id / 3; }
    else                 { int id = bid - 4288; W = W_out; WT = WoutT; K = DI_; N = 1024; bx = id & 31; by = id >> 5; }
    __shared__ float tile[32][33];
    int k0 = by * 32, n0 = bx * 32;
    int tr = threadIdx.x >> 5;
    int tc = threadIdx.x & 31;
#pragma unroll
    for (int i = 0; i < 4; ++i)
        tile[tr + i*8][tc] = W[(size_t)(k0 + tr + i*8) * N + n0 + tc];
    __syncthreads();
#pragma unroll
    for (int i = 0; i < 4; ++i)
        WT[(size_t)(n0 + tr + i*8) * K + k0 + tc] = f2bf(tile[tc][tr + i*8]);
}

// ---------------- MFMA bf16 GEMM: C(MxN) = A(MxK) * BT(NxK)^T ----------------
// MODE 0: plain store. MODE 1: atomicAdd. MODE 3: xz-split (col<DI -> xi fp32; col>=DI -> silu bf16)
// MODE 4: per-z partial slices (C + z*BL*ldc), plain store.
// XCD-aware bijective swizzle on the (bx,by) flat id (requires gridDim.x*gridDim.y % 8 == 0).
template <int BN, int MODE>
__global__ __launch_bounds__(256) void mfma_gemm_bt(
        const unsigned short* __restrict__ A,  int lda,
        const unsigned short* __restrict__ BT, int ldb,
        float* __restrict__ C, int ldc, int Kchunk,
        float* __restrict__ xi, unsigned short* __restrict__ sz) {
    constexpr int NT = BN / 32;
    __shared__ unsigned short As[128 * 32];
    __shared__ unsigned short Bs[BN * 32];

    int tid = threadIdx.x;
    int wave = tid >> 6, lane = tid & 63;
    int lane15 = lane & 15, quad = lane >> 4;
    int wr = wave >> 1, wc = wave & 1;

    int nxy = gridDim.x * gridDim.y;
    int flat = blockIdx.y * gridDim.x + blockIdx.x;
    int cpx = nxy >> 3;
    int swz = (flat & 7) * cpx + (flat >> 3);
    int bx = swz % gridDim.x;
    int by = swz / gridDim.x;

    int m0 = by * 128;
    int n0 = bx * BN;
    int kbeg = blockIdx.z * Kchunk;
    int kend = kbeg + Kchunk;

    f32x4 acc[4][NT];
#pragma unroll
    for (int i = 0; i < 4; ++i)
#pragma unroll
        for (int j = 0; j < NT; ++j) acc[i][j] = (f32x4){0.f, 0.f, 0.f, 0.f};

    constexpr int ACALLS = 8;
    constexpr int BCALLS = BN * 4 / 64;

    for (int k0 = kbeg; k0 < kend; k0 += 32) {
        __syncthreads();
        for (int c = wave; c < ACALLS + BCALLS; c += 4) {
            if (c < ACALLS) {
                int cell = c * 64 + lane;
                int m = cell >> 2, s = cell & 3;
                int q = s ^ (m & 3) ^ ((m >> 2) & 3);
                gl_lds16(A + (size_t)(m0 + m) * lda + k0 + q * 8, &As[c * 512]);
            } else {
                int cell = (c - ACALLS) * 64 + lane;
                int n = cell >> 2, s = cell & 3;
                int q = s ^ (n & 3) ^ ((n >> 2) & 3);
                gl_lds16(BT + (size_t)(n0 + n) * ldb + k0 + q * 8, &Bs[(c - ACALLS) * 512]);
            }
        }
        __syncthreads();

        short8 af[4], bfr[NT];
#pragma unroll
        for (int i = 0; i < 4; ++i) {
            int m = wr * 64 + i * 16 + lane15;
            int s = quad ^ (m & 3) ^ ((m >> 2) & 3);
            af[i] = *(const short8*)&As[m * 32 + s * 8];
        }
#pragma unroll
        for (int j = 0; j < NT; ++j) {
            int n = wc * (NT * 16) + j * 16 + lane15;
            int s = quad ^ (n & 3) ^ ((n >> 2) & 3);
            bfr[j] = *(const short8*)&Bs[n * 32 + s * 8];
        }
#pragma unroll
        for (int i = 0; i < 4; ++i)
#pragma unroll
            for (int j = 0; j < NT; ++j)
                acc[i][j] = __builtin_amdgcn_mfma_f32_16x16x32_bf16(af[i], bfr[j], acc[i][j], 0, 0, 0);
    }

#pragma unroll
    for (int i = 0; i < 4; ++i) {
        int row = m0 + wr * 64 + i * 16 + quad * 4;
#pragma unroll
        for (int j = 0; j < NT; ++j) {
            int col = n0 + wc * (NT * 16) + j * 16 + lane15;
#pragma unroll
            for (int r = 0; r < 4; ++r) {
                float v = acc[i][j][r];
                int rr = row + r;
                if (MODE == 0) {
                    C[(size_t)rr * ldc + col] = v;
                } else if (MODE == 1) {
                    atomicAdd(&C[(size_t)rr * ldc + col], v);
                } else if (MODE == 4) {
                    C[((size_t)blockIdx.z * BL_ + rr) * ldc + col] = v;
                } else {   // MODE 3
                    if (col < DI_) xi[(size_t)rr * DI_ + col] = v;
                    else           sz[(size_t)rr * DI_ + (col - DI_)] = f2bf(fast_silu(v));
                }
            }
        }
    }
}

// ---------------- Causal depthwise conv (K=4) + SiLU -> bf16 (4 ch/thread, float4) ----------------
__global__ void conv_silu_kernel(const float* __restrict__ xi, const float* __restrict__ cw,
                                 const float* __restrict__ cb, unsigned short* __restrict__ ub) {
    int t = blockIdx.x * blockDim.x + threadIdx.x;     // 0 .. BL*DI/4-1
    int c = (t << 2) & (DI_ - 1);
    int bl = t >> 9;
    int l = bl & (L_ - 1);
    float4 w0 = ((const float4*)cw)[c + 0];
    float4 w1 = ((const float4*)cw)[c + 1];
    float4 w2 = ((const float4*)cw)[c + 2];
    float4 w3 = ((const float4*)cw)[c + 3];
    float4 bias = *(const float4*)&cb[c];
    const float* base = xi + (size_t)bl * DI_ + c;
    float4 a = bias;
    float4 x0 = *(const float4*)base;
    a.x = fmaf(x0.x, w0.w, a.x); a.y = fmaf(x0.y, w1.w, a.y);
    a.z = fmaf(x0.z, w2.w, a.z); a.w = fmaf(x0.w, w3.w, a.w);
    if (l >= 1) {
        float4 x1 = *(const float4*)(base - DI_);
        a.x = fmaf(x1.x, w0.z, a.x); a.y = fmaf(x1.y, w1.z, a.y);
        a.z = fmaf(x1.z, w2.z, a.z); a.w = fmaf(x1.w, w3.z, a.w);
    }
    if (l >= 2) {
        float4 x2 = *(const float4*)(base - 2 * DI_);
        a.x = fmaf(x2.x, w0.y, a.x); a.y = fmaf(x2.y, w1.y, a.y);
        a.z = fmaf(x2.z, w2.y, a.z); a.w = fmaf(x2.w, w3.y, a.w);
    }
    if (l >= 3) {
        float4 x3 = *(const float4*)(base - 3 * DI_);
        a.x = fmaf(x3.x, w0.x, a.x); a.y = fmaf(x3.y, w1.x, a.y);
        a.z = fmaf(x3.z, w2.x, a.z); a.w = fmaf(x3.w, w3.x, a.w);
    }
    ushort4 o;
    o.x = f2bf(fast_silu(a.x));
    o.y = f2bf(fast_silu(a.y));
    o.z = f2bf(fast_silu(a.z));
    o.w = f2bf(fast_silu(a.w));
    *(ushort4*)&ub[(size_t)bl * DI_ + c] = o;
}

// ---------------- Reduce split-K partials: proj = sum_z projp[z] ----------------
__global__ void reduce_proj(const float* __restrict__ projp, float* __restrict__ proj) {
    int idx = blockIdx.x * blockDim.x + threadIdx.x;   // 0 .. BL*24-1
    int bl = idx / 24;
    int c4 = idx - bl * 24;
    const float4* src = (const float4*)projp;
    float4 s = src[(size_t)bl * 24 + c4];
#pragma unroll
    for (int z = 1; z < 16; ++z) {
        float4 v = src[((size_t)z * BL_ + bl) * 24 + c4];
        s.x += v.x; s.y += v.y; s.z += v.z; s.w += v.w;
    }
    ((float4*)proj)[(size_t)bl * 24 + c4] = s;
}

// ---------------- Fused dt-GEMM + softplus + pack + transpose ----------------
// dt[bl][c] = softplus(proj[bl,:64] @ W_dt[:,c] + b_dt[c]); writes
// dtduT[c*BL+bl] = {dt, dt*u} fp32 and szdT[c*BL+bl] = {hi: bf16(u*D*sz), lo: bf16(sz)}
__global__ __launch_bounds__(256) void dtprep(
        const float* __restrict__ proj, const float* __restrict__ W_dt,
        const float* __restrict__ b_dt, const unsigned short* __restrict__ ub,
        const unsigned short* __restrict__ szb, const float* __restrict__ Dp,
        float2* __restrict__ dtduT, unsigned int* __restrict__ szdT) {
    __shared__ alignas(16) unsigned char smem[64 * 65 * 8];   // 33280 B, multi-purpose
    float (*As)[68] = reinterpret_cast<float(*)[68]>(smem);           // 16x68x4 = 4352
    float (*Bs)[64] = reinterpret_cast<float(*)[64]>(smem + 4352);    // 16x64x4 = 4096
    float2 (*T2)[65] = reinterpret_cast<float2(*)[65]>(smem);         // 64x65x8
    unsigned int (*TU)[65] = reinterpret_cast<unsigned int(*)[65]>(smem); // 64x65x4

    int tid = threadIdx.x;
    int n0 = blockIdx.x * 64;   // c tile
    int m0 = blockIdx.y * 64;   // bl tile
    int ar = tid >> 2, ak = (tid & 3) << 2;
    int kb = tid >> 4, bc = (tid & 15) << 2;
    int ty = tid >> 4, tx = tid & 15;

    float acc[4][4] = {};
#pragma unroll
    for (int k0 = 0; k0 < R_; k0 += 16) {
        float4 av = *(const float4*)&proj[(size_t)(m0 + ar) * 96 + k0 + ak];
        As[ak + 0][ar] = av.x; As[ak + 1][ar] = av.y;
        As[ak + 2][ar] = av.z; As[ak + 3][ar] = av.w;
        float4 bv = *(const float4*)&W_dt[(size_t)(k0 + kb) * DI_ + n0 + bc];
        Bs[kb][bc + 0] = bv.x; Bs[kb][bc + 1] = bv.y;
        Bs[kb][bc + 2] = bv.z; Bs[kb][bc + 3] = bv.w;
        __syncthreads();
#pragma unroll
        for (int kk = 0; kk < 16; ++kk) {
            float a[4], bb[4];
#pragma unroll
            for (int i = 0; i < 4; ++i) a[i] = As[kk][ty * 4 + i];
#pragma unroll
            for (int j = 0; j < 4; ++j) bb[j] = Bs[kk][tx * 4 + j];
#pragma unroll
            for (int i = 0; i < 4; ++i)
#pragma unroll
                for (int j = 0; j < 4; ++j)
                    acc[i][j] = fmaf(a[i], bb[j], acc[i][j]);
        }
        __syncthreads();
    }

    // epilogue regs
    float4 bd = *(const float4*)&b_dt[n0 + tx * 4];
    float4 dp4 = *(const float4*)&Dp[n0 + tx * 4];
    float bda[4] = {bd.x, bd.y, bd.z, bd.w};
    float dpa[4] = {dp4.x, dp4.y, dp4.z, dp4.w};
    float2 d2[4][4];
    unsigned int su[4][4];
#pragma unroll
    for (int i = 0; i < 4; ++i) {
        int bl = m0 + ty * 4 + i;
        ushort4 u4 = *(const ushort4*)&ub[(size_t)bl * DI_ + n0 + tx * 4];
        ushort4 s4 = *(const ushort4*)&szb[(size_t)bl * DI_ + n0 + tx * 4];
        unsigned short ua[4] = {u4.x, u4.y, u4.z, u4.w};
        unsigned short sa[4] = {s4.x, s4.y, s4.z, s4.w};
#pragma unroll
        for (int j = 0; j < 4; ++j) {
            float v = acc[i][j] + bda[j];
            float dtv = fmaxf(v, 0.f) + __logf(1.f + __expf(-fabsf(v)));
            float uu = bf2f(ua[j]);
            float szv = bf2f(sa[j]);
            d2[i][j] = make_float2(dtv, dtv * uu);
            su[i][j] = ((unsigned)f2bf(uu * dpa[j] * szv) << 16) | (unsigned)f2bf(szv);
        }
    }

    // pass 1: {dt, dtu} transpose through LDS
#pragma unroll
    for (int i = 0; i < 4; ++i)
#pragma unroll
        for (int j = 0; j < 4; ++j)
            T2[ty * 4 + i][tx * 4 + j] = d2[i][j];
    __syncthreads();
#pragma unroll
    for (int i = 0; i < 8; ++i) {
        int c_l = (tid >> 5) + i * 8;
#pragma unroll
        for (int jj = 0; jj < 2; ++jj) {
            int bl_l = (tid & 31) + jj * 32;
            dtduT[(size_t)(n0 + c_l) * BL_ + m0 + bl_l] = T2[bl_l][c_l];
        }
    }
    __syncthreads();

    // pass 2: szd transpose through LDS
#pragma unroll
    for (int i = 0; i < 4; ++i)
#pragma unroll
        for (int j = 0; j < 4; ++j)
            TU[ty * 4 + i][tx * 4 + j] = su[i][j];
    __syncthreads();
#pragma unroll
    for (int i = 0; i < 8; ++i) {
        int c_l = (tid >> 5) + i * 8;
#pragma unroll
        for (int jj = 0; jj < 2; ++jj) {
            int bl_l = (tid & 31) + jj * 32;
            szdT[(size_t)(n0 + c_l) * BL_ + m0 + bl_l] = TU[bl_l][c_l];
        }
    }
}

// ---------------- Scan v11: v8 exact (best measured: 47.4 us) ----------------
// 2 channels/block, 512 thr, 16 chunks x 64 l. dd staged in LDS (single HBM pass);
// B/C read n-contiguous from proj (16-lane broadcast, L2-resident). Staggered LDS.
__global__ __launch_bounds__(512, 8) void scan_v11(
        const float2* __restrict__ dtduT, const unsigned int* __restrict__ szdT,
        const float* __restrict__ proj, const float* __restrict__ A_log,
        unsigned short* __restrict__ yzT) {
    int bc = blockIdx.x;            // 0..2047
    int b = bc >> 10;
    int cp = bc & 1023;
    int t = threadIdx.x;            // 0..511
    int n = t & 15;
    int cs = (t >> 4) & 1;
    int chunk = t >> 5;             // 0..15, 64 l each
    int c = cp * 2 + cs;

    __shared__ float dd[2][2120];   // {dt,dtu} interleaved, il2 layout, 8-float cs stagger
    __shared__ float sA[16][32];
    __shared__ float sB[16][32];
    __shared__ float ps[2][1096];   // IDX4 layout, 8-float cs stagger

    {   // stage both channel streams, coalesced: 512 threads x 4 l (32 B each)
        int half = t >> 8;
        int tt = t & 255;
        int l = tt * 4;
        int cload = cp * 2 + half;
        const float4* g = (const float4*)(dtduT + (size_t)cload * BL_ + (size_t)b * L_ + l);
        int il2 = l + ((l >> 6) << 1);
        float* dst = &dd[half][il2 * 2];
        *(float4*)(dst + 0) = g[0];
        *(float4*)(dst + 4) = g[1];
    }
    __syncthreads();

    float A2 = -__expf(A_log[c * N_ + n]) * 1.4426950408889634f;  // fold log2(e)
    int lb = chunk * 64;
    const float* ddp = &dd[cs][(lb + ((lb >> 6) << 1)) * 2];
    const float* pB = proj + (size_t)b * L_ * 96 + R_ + n + (size_t)lb * 96;
    const float* pC = pB + N_;

    // Phase 1: chunk-local scan over 64 l
    float a = 1.f, acc = 0.f;
#pragma unroll
    for (int q = 0; q < 16; ++q) {
        float4 d0 = *(const float4*)(ddp + q * 8);
        float4 d1 = *(const float4*)(ddp + q * 8 + 4);
        float b0 = pB[(q*4 + 0) * 96];
        float b1 = pB[(q*4 + 1) * 96];
        float b2 = pB[(q*4 + 2) * 96];
        float b3 = pB[(q*4 + 3) * 96];
        float e;
        e = fexp2(d0.x * A2); a *= e; acc = fmaf(e, acc, d0.y * b0);
        e = fexp2(d0.z * A2); a *= e; acc = fmaf(e, acc, d0.w * b1);
        e = fexp2(d1.x * A2); a *= e; acc = fmaf(e, acc, d1.y * b2);
        e = fexp2(d1.z * A2); a *= e; acc = fmaf(e, acc, d1.w * b3);
    }
    sA[chunk][cs * 16 + n] = a;
    sB[chunk][cs * 16 + n] = acc;
    __syncthreads();

    // Phase 2: serial combine across 16 chunks (32 threads: one per (cs,n))
    if (t < 32) {
        float hc = 0.f;
#pragma unroll
        for (int j = 0; j < 16; ++j) {
            float aj = sA[j][t];
            float bj = sB[j][t];
            sB[j][t] = hc;
            hc = fmaf(aj, hc, bj);
        }
    }
    __syncthreads();
    float h = sB[chunk][cs * 16 + n];

    // Phase 3: re-walk; DPP row-sum -> lane n==15 of each 16-lane group
    float* psb = &ps[cs][IDX4(lb)];
#pragma unroll
    for (int q = 0; q < 16; ++q) {
        float4 d0 = *(const float4*)(ddp + q * 8);
        float4 d1 = *(const float4*)(ddp + q * 8 + 4);
        float b0 = pB[(q*4 + 0) * 96], c0 = pC[(q*4 + 0) * 96];
        float b1 = pB[(q*4 + 1) * 96], c1 = pC[(q*4 + 1) * 96];
        float b2 = pB[(q*4 + 2) * 96], c2 = pC[(q*4 + 2) * 96];
        float b3 = pB[(q*4 + 3) * 96], c3 = pC[(q*4 + 3) * 96];
        float e, p0, p1, p2, p3;
        e = fexp2(d0.x * A2); h = fmaf(e, h, d0.y * b0); p0 = row16_sum(h * c0);
        e = fexp2(d0.z * A2); h = fmaf(e, h, d0.w * b1); p1 = row16_sum(h * c1);
        e = fexp2(d1.x * A2); h = fmaf(e, h, d1.y * b2); p2 = row16_sum(h * c2);
        e = fexp2(d1.z * A2); h = fmaf(e, h, d1.w * b3); p3 = row16_sum(h * c3);
        if (n == 15) *(float4*)&psb[q * 4] = (float4){p0, p1, p2, p3};
    }
    __syncthreads();

    // Epilogue: y = p * sz + u*D*sz, 4 per thread, coalesced (256 threads per channel)
    {
        int half = t >> 8;
        int tt = t & 255;
        int l = tt * 4;
        int c_out = cp * 2 + half;
        size_t tb = (size_t)c_out * BL_ + (size_t)b * L_;
        const float* pp = &ps[half][IDX4(l)];
        float4 p4 = *(const float4*)pp;
        uint4 sd4 = *(const uint4*)(szdT + tb + l);
        ushort4 o;
        o.x = f2bf(p4.x * bf2f((unsigned short)(sd4.x & 0xffff)) + bf2f((unsigned short)(sd4.x >> 16)));
        o.y = f2bf(p4.y * bf2f((unsigned short)(sd4.y & 0xffff)) + bf2f((unsigned short)(sd4.y >> 16)));
        o.z = f2bf(p4.z * bf2f((unsigned short)(sd4.z & 0xffff)) + bf2f((unsigned short)(sd4.z >> 16)));
        o.w = f2bf(p4.w * bf2f((unsigned short)(sd4.w & 0xffff)) + bf2f((unsigned short)(sd4.w >> 16)));
        *(ushort4*)(yzT + tb + l) = o;
    }
}

// ---------------- Transpose back: yzT (DI x BL) -> yzb (BL x DI) ----------------
__global__ void transpose_y(const unsigned short* __restrict__ yzT, unsigned short* __restrict__ yz) {
    __shared__ unsigned short t[32][33];
    int c0 = blockIdx.y * 32, bl0 = blockIdx.x * 32;
    int r = threadIdx.x >> 5;
    int col = threadIdx.x & 31;
#pragma unroll
    for (int i = 0; i < 4; ++i)
        t[r + i*8][col] = yzT[(size_t)(c0 + r + i*8) * BL_ + bl0 + col];
    __syncthreads();
#pragma unroll
    for (int i = 0; i < 4; ++i)
        yz[(size_t)(bl0 + r + i*8) * DI_ + c0 + col] = t[col][r + i*8];
}

extern "C" void kernel_launch(void* const* d_in, const int* in_sizes, int n_in,
                              void* d_out, int out_size, void* d_ws, size_t ws_size,
                              hipStream_t stream) {
    const float* x       = (const float*)d_in[0];
    const float* ln_w    = (const float*)d_in[1];
    const float* ln_b    = (const float*)d_in[2];
    const float* W_in    = (const float*)d_in[3];
    const float* conv_w  = (const float*)d_in[4];
    const float* conv_b  = (const float*)d_in[5];
    const float* W_x     = (const float*)d_in[6];
    const float* W_dt    = (const float*)d_in[7];
    const float* b_dt    = (const float*)d_in[8];
    const float* A_log   = (const float*)d_in[9];
    const float* D_param = (const float*)d_in[10];
    const float* W_out   = (const float*)d_in[11];
    float* out = (float*)d_out;

    uint8_t* p = (uint8_t*)d_ws;
    unsigned short* hb    = (unsigned short*)p;  p += (size_t)BL_ * D_ * 2;          // 4 MB  (dead after GEMM2)
    unsigned short* WinT  = (unsigned short*)p;  p += (size_t)4096 * 1024 * 2;       // 8 MB  (dead after GEMM2)
    float*          xib   = (float*)p;           p += (size_t)BL_ * DI_ * 4;         // 16 MB
    unsigned short* szb   = (unsigned short*)p;  p += (size_t)BL_ * DI_ * 2;         // 8 MB
    unsigned short* ub    = (unsigned short*)p;  p += (size_t)BL_ * DI_ * 2;         // 8 MB
    unsigned short* WxT   = (unsigned short*)p;  p += (size_t)96 * DI_ * 2;          // 0.375 MB
    float*          proj  = (float*)p;           p += (size_t)BL_ * 96 * 4;          // 0.75 MB
    unsigned short* WoutT = (unsigned short*)p;  p += (size_t)1024 * DI_ * 2;        // 4 MB
    float2*         dtduT = (float2*)p;          p += (size_t)BL_ * DI_ * 8;         // 32 MB
    unsigned int*   szdT  = (unsigned int*)p;    p += (size_t)BL_ * DI_ * 4;         // 16 MB
    unsigned short* yzT   = (unsigned short*)p;  p += (size_t)BL_ * DI_ * 2;         // 8 MB
    // projp (12 MB) aliases the dead hb+WinT region [0, 12MB): hb/WinT dead after GEMM2;
    // projp written by GEMM4 (MODE 4), read by reduce_proj; dead before transpose_y writes yzb.
    float*          projp = (float*)d_ws;
    // yzb aliases the dead hb+WinT region (8 MB <= 12 MB; written after projp is dead)
    unsigned short* yzb   = (unsigned short*)d_ws;

    hipMemcpyAsync(out, x, (size_t)BL_ * D_ * 4, hipMemcpyDeviceToDevice, stream);

    // weight transposes (one dispatch)
    transpose_cast_all<<<6336, 256, 0, stream>>>(W_in, W_x, W_out, WinT, WxT, WoutT);

    // 1. LayerNorm -> bf16
    ln_kernel<<<BL_, 256, 0, stream>>>(x, ln_w, ln_b, hb);

    // 2. xz = h @ W_in  (MFMA; epilogue splits xi fp32 / silu(z) bf16)
    mfma_gemm_bt<128, 3><<<dim3(4096 / 128, BL_ / 128, 1), 256, 0, stream>>>(
        hb, 1024, WinT, 1024, nullptr, 0, 1024, xib, szb);

    // 3. u = silu(conv(xi)) -> bf16  (4 channels/thread, float4)
    conv_silu_kernel<<<(BL_ * DI_) / 1024, 256, 0, stream>>>(xib, conv_w, conv_b, ub);

    // 4. projp[z] = u @ W_x (z-th K-slice)  (MFMA, split-K=16, plain stores)
    mfma_gemm_bt<96, 4><<<dim3(1, BL_ / 128, 16), 256, 0, stream>>>(
        ub, DI_, WxT, DI_, projp, 96, 128, nullptr, nullptr);

    // 4b. proj = sum_z projp[z]
    reduce_proj<<<(BL_ * 24) / 256, 256, 0, stream>>>(projp, proj);

    // 5. fused dt-GEMM + softplus + pack + transpose
    dtprep<<<dim3(DI_ / 64, BL_ / 64), 256, 0, stream>>>(
        proj, W_dt, b_dt, ub, szb, D_param, dtduT, szdT);

    // 6. scan v11 (= v8, best measured) -> yzT
    scan_v11<<<B_ * DI_ / 2, 512, 0, stream>>>(dtduT, szdT, proj, A_log, yzT);

    // 6b. yzT -> row-major yzb
    transpose_y<<<dim3(BL_ / 32, DI_ / 32), 256, 0, stream>>>(yzT, yzb);

    // 7. out += yz @ W_out  (MFMA, split-K=4 atomic onto residual)
    mfma_gemm_bt<128, 1><<<dim3(1024 / 128, BL_ / 128, 4), 256, 0, stream>>>(
        yzb, DI_, WoutT, DI_, out, 1024, 512, nullptr, nullptr);
}

// Round 8
// 270.517 us; speedup vs baseline: 1.0437x; 1.0437x over previous
//
#include <hip/hip_runtime.h>
#include <hip/hip_bf16.h>
#include <math.h>

#define B_ 2
#define L_ 1024
#define D_ 1024
#define DI_ 2048
#define K_ 4
#define N_ 16
#define R_ 64
#define BL_ (B_ * L_)
#define EPS_ 1e-5f

#define IDX4(l) ((l) + (((l) >> 6) << 2))

typedef __attribute__((ext_vector_type(8))) short short8;
typedef __attribute__((ext_vector_type(4))) float f32x4;

__device__ inline unsigned short f2bf(float f) {
    unsigned u = __float_as_uint(f);
    unsigned r = (u + 0x7fffu + ((u >> 16) & 1u)) >> 16;
    return (unsigned short)r;
}
__device__ inline float bf2f(unsigned short s) {
    return __uint_as_float(((unsigned)s) << 16);
}
__device__ inline float fast_silu(float z) {
    return z * __builtin_amdgcn_rcpf(1.f + __expf(-z));
}
#if __has_builtin(__builtin_amdgcn_exp2f)
__device__ inline float fexp2(float x) { return __builtin_amdgcn_exp2f(x); }
#else
__device__ inline float fexp2(float x) { return exp2f(x); }
#endif
__device__ inline void gl_lds16(const void* g, void* l) {
    __builtin_amdgcn_global_load_lds(
        (const __attribute__((address_space(1))) void*)g,
        (__attribute__((address_space(3))) void*)l, 16, 0, 0);
}

// DPP row_shr; row = 16 lanes. Sum lands in lane (n==15) of each 16-lane row. [verified R5/R6]
template <int CTRL>
__device__ inline float dpp_shr(float x) {
    return __int_as_float(__builtin_amdgcn_update_dpp(
        0, __float_as_int(x), CTRL, 0xf, 0xf, true));
}
__device__ inline float row16_sum(float p) {
    p += dpp_shr<0x111>(p);
    p += dpp_shr<0x112>(p);
    p += dpp_shr<0x114>(p);
    p += dpp_shr<0x118>(p);
    return p;
}

// ---------------- LayerNorm -> bf16 ----------------
__global__ void ln_kernel(const float* __restrict__ x, const float* __restrict__ w,
                          const float* __restrict__ b, unsigned short* __restrict__ hb) {
    int row = blockIdx.x;
    const float* xr = x + (size_t)row * D_;
    float4 v = ((const float4*)xr)[threadIdx.x];

    __shared__ float red[4];
    float s = v.x + v.y + v.z + v.w;
    for (int off = 1; off < 64; off <<= 1) s += __shfl_xor(s, off, 64);
    if ((threadIdx.x & 63) == 0) red[threadIdx.x >> 6] = s;
    __syncthreads();
    float mu = (red[0] + red[1] + red[2] + red[3]) * (1.0f / D_);
    __syncthreads();
    float cx = v.x - mu, cy = v.y - mu, cz = v.z - mu, cw = v.w - mu;
    float sq = cx*cx + cy*cy + cz*cz + cw*cw;
    for (int off = 1; off < 64; off <<= 1) sq += __shfl_xor(sq, off, 64);
    if ((threadIdx.x & 63) == 0) red[threadIdx.x >> 6] = sq;
    __syncthreads();
    float var = (red[0] + red[1] + red[2] + red[3]) * (1.0f / D_);
    float rstd = rsqrtf(var + EPS_);

    float4 wv = ((const float4*)w)[threadIdx.x];
    float4 bv = ((const float4*)b)[threadIdx.x];
    ushort4 o;
    o.x = f2bf(cx * rstd * wv.x + bv.x);
    o.y = f2bf(cy * rstd * wv.y + bv.y);
    o.z = f2bf(cz * rstd * wv.z + bv.z);
    o.w = f2bf(cw * rstd * wv.w + bv.w);
    ((ushort4*)(hb + (size_t)row * D_))[threadIdx.x] = o;
}

// ---------------- Merged transpose+cast of all three weights ----------------
__global__ void transpose_cast_all(const float* __restrict__ W_in, const float* __restrict__ W_x,
                                   const float* __restrict__ W_out,
                                   unsigned short* __restrict__ WinT, unsigned short* __restrict__ WxT,
                                   unsigned short* __restrict__ WoutT) {
    int bid = blockIdx.x;
    const float* W; unsigned short* WT; int K, N, bx, by;
    if (bid < 4096)      { W = W_in;  WT = WinT;  K = 1024; N = 4096; bx = bid & 127; by = bid >> 7; }
    else if (bid < 4288) { int id = bid - 4096; W = W_x;  WT = WxT;  K = DI_; N = 96;   bx = id % 3;  by = id / 3; }
    else                 { int id = bid - 4288; W = W_out; WT = WoutT; K = DI_; N = 1024; bx = id & 31; by = id >> 5; }
    __shared__ float tile[32][33];
    int k0 = by * 32, n0 = bx * 32;
    int tr = threadIdx.x >> 5;
    int tc = threadIdx.x & 31;
#pragma unroll
    for (int i = 0; i < 4; ++i)
        tile[tr + i*8][tc] = W[(size_t)(k0 + tr + i*8) * N + n0 + tc];
    __syncthreads();
#pragma unroll
    for (int i = 0; i < 4; ++i)
        WT[(size_t)(n0 + tr + i*8) * K + k0 + tc] = f2bf(tile[tc][tr + i*8]);
}

// ---------------- MFMA bf16 GEMM: C(MxN) = A(MxK) * BT(NxK)^T ----------------
// Wave grid 2x2: per-wave m-frags MR=BM/32, n-frags NT=BN/32.
// MODE 0: plain store. MODE 1: atomicAdd. MODE 3: xz-split (col<DI -> xi fp32; col>=DI -> silu bf16)
// MODE 4: per-z partial slices (C + z*BL*ldc), plain store.
// XCD-aware bijective swizzle on the (bx,by) flat id (requires gridDim.x*gridDim.y % 8 == 0).
template <int BM, int BN, int MODE>
__global__ __launch_bounds__(256) void mfma_gemm_bt(
        const unsigned short* __restrict__ A,  int lda,
        const unsigned short* __restrict__ BT, int ldb,
        float* __restrict__ C, int ldc, int Kchunk,
        float* __restrict__ xi, unsigned short* __restrict__ sz) {
    constexpr int MR = BM / 32;
    constexpr int NT = BN / 32;
    __shared__ unsigned short As[BM * 32];
    __shared__ unsigned short Bs[BN * 32];

    int tid = threadIdx.x;
    int wave = tid >> 6, lane = tid & 63;
    int lane15 = lane & 15, quad = lane >> 4;
    int wr = wave >> 1, wc = wave & 1;

    int nxy = gridDim.x * gridDim.y;
    int flat = blockIdx.y * gridDim.x + blockIdx.x;
    int cpx = nxy >> 3;
    int swz = (flat & 7) * cpx + (flat >> 3);
    int bx = swz % gridDim.x;
    int by = swz / gridDim.x;

    int m0 = by * BM;
    int n0 = bx * BN;
    int kbeg = blockIdx.z * Kchunk;
    int kend = kbeg + Kchunk;

    f32x4 acc[MR][NT];
#pragma unroll
    for (int i = 0; i < MR; ++i)
#pragma unroll
        for (int j = 0; j < NT; ++j) acc[i][j] = (f32x4){0.f, 0.f, 0.f, 0.f};

    constexpr int ACALLS = BM / 16;
    constexpr int BCALLS = BN / 16;

    for (int k0 = kbeg; k0 < kend; k0 += 32) {
        __syncthreads();
        for (int c = wave; c < ACALLS + BCALLS; c += 4) {
            if (c < ACALLS) {
                int cell = c * 64 + lane;
                int m = cell >> 2, s = cell & 3;
                int q = s ^ (m & 3) ^ ((m >> 2) & 3);
                gl_lds16(A + (size_t)(m0 + m) * lda + k0 + q * 8, &As[c * 512]);
            } else {
                int cell = (c - ACALLS) * 64 + lane;
                int n = cell >> 2, s = cell & 3;
                int q = s ^ (n & 3) ^ ((n >> 2) & 3);
                gl_lds16(BT + (size_t)(n0 + n) * ldb + k0 + q * 8, &Bs[(c - ACALLS) * 512]);
            }
        }
        __syncthreads();

        short8 af[MR], bfr[NT];
#pragma unroll
        for (int i = 0; i < MR; ++i) {
            int m = wr * (MR * 16) + i * 16 + lane15;
            int s = quad ^ (m & 3) ^ ((m >> 2) & 3);
            af[i] = *(const short8*)&As[m * 32 + s * 8];
        }
#pragma unroll
        for (int j = 0; j < NT; ++j) {
            int n = wc * (NT * 16) + j * 16 + lane15;
            int s = quad ^ (n & 3) ^ ((n >> 2) & 3);
            bfr[j] = *(const short8*)&Bs[n * 32 + s * 8];
        }
#pragma unroll
        for (int i = 0; i < MR; ++i)
#pragma unroll
            for (int j = 0; j < NT; ++j)
                acc[i][j] = __builtin_amdgcn_mfma_f32_16x16x32_bf16(af[i], bfr[j], acc[i][j], 0, 0, 0);
    }

#pragma unroll
    for (int i = 0; i < MR; ++i) {
        int row = m0 + wr * (MR * 16) + i * 16 + quad * 4;
#pragma unroll
        for (int j = 0; j < NT; ++j) {
            int col = n0 + wc * (NT * 16) + j * 16 + lane15;
#pragma unroll
            for (int r = 0; r < 4; ++r) {
                float v = acc[i][j][r];
                int rr = row + r;
                if (MODE == 0) {
                    C[(size_t)rr * ldc + col] = v;
                } else if (MODE == 1) {
                    atomicAdd(&C[(size_t)rr * ldc + col], v);
                } else if (MODE == 4) {
                    C[((size_t)blockIdx.z * BL_ + rr) * ldc + col] = v;
                } else {   // MODE 3
                    if (col < DI_) xi[(size_t)rr * DI_ + col] = v;
                    else           sz[(size_t)rr * DI_ + (col - DI_)] = f2bf(fast_silu(v));
                }
            }
        }
    }
}

// ---------------- Causal depthwise conv (K=4) + SiLU -> bf16 (4 ch/thread, float4) ----------------
__global__ void conv_silu_kernel(const float* __restrict__ xi, const float* __restrict__ cw,
                                 const float* __restrict__ cb, unsigned short* __restrict__ ub) {
    int t = blockIdx.x * blockDim.x + threadIdx.x;     // 0 .. BL*DI/4-1
    int c = (t << 2) & (DI_ - 1);
    int bl = t >> 9;
    int l = bl & (L_ - 1);
    float4 w0 = ((const float4*)cw)[c + 0];
    float4 w1 = ((const float4*)cw)[c + 1];
    float4 w2 = ((const float4*)cw)[c + 2];
    float4 w3 = ((const float4*)cw)[c + 3];
    float4 bias = *(const float4*)&cb[c];
    const float* base = xi + (size_t)bl * DI_ + c;
    float4 a = bias;
    float4 x0 = *(const float4*)base;
    a.x = fmaf(x0.x, w0.w, a.x); a.y = fmaf(x0.y, w1.w, a.y);
    a.z = fmaf(x0.z, w2.w, a.z); a.w = fmaf(x0.w, w3.w, a.w);
    if (l >= 1) {
        float4 x1 = *(const float4*)(base - DI_);
        a.x = fmaf(x1.x, w0.z, a.x); a.y = fmaf(x1.y, w1.z, a.y);
        a.z = fmaf(x1.z, w2.z, a.z); a.w = fmaf(x1.w, w3.z, a.w);
    }
    if (l >= 2) {
        float4 x2 = *(const float4*)(base - 2 * DI_);
        a.x = fmaf(x2.x, w0.y, a.x); a.y = fmaf(x2.y, w1.y, a.y);
        a.z = fmaf(x2.z, w2.y, a.z); a.w = fmaf(x2.w, w3.y, a.w);
    }
    if (l >= 3) {
        float4 x3 = *(const float4*)(base - 3 * DI_);
        a.x = fmaf(x3.x, w0.x, a.x); a.y = fmaf(x3.y, w1.x, a.y);
        a.z = fmaf(x3.z, w2.x, a.z); a.w = fmaf(x3.w, w3.x, a.w);
    }
    ushort4 o;
    o.x = f2bf(fast_silu(a.x));
    o.y = f2bf(fast_silu(a.y));
    o.z = f2bf(fast_silu(a.z));
    o.w = f2bf(fast_silu(a.w));
    *(ushort4*)&ub[(size_t)bl * DI_ + c] = o;
}

// ---------------- Reduce split-K partials: proj = sum_z projp[z] ----------------
__global__ void reduce_proj(const float* __restrict__ projp, float* __restrict__ proj) {
    int idx = blockIdx.x * blockDim.x + threadIdx.x;   // 0 .. BL*24-1
    int bl = idx / 24;
    int c4 = idx - bl * 24;
    const float4* src = (const float4*)projp;
    float4 s = src[(size_t)bl * 24 + c4];
#pragma unroll
    for (int z = 1; z < 16; ++z) {
        float4 v = src[((size_t)z * BL_ + bl) * 24 + c4];
        s.x += v.x; s.y += v.y; s.z += v.z; s.w += v.w;
    }
    ((float4*)proj)[(size_t)bl * 24 + c4] = s;
}

// ---------------- Fused dt-GEMM + softplus + pack + transpose ----------------
// dt[bl][c] = softplus(proj[bl,:64] @ W_dt[:,c] + b_dt[c]); writes
// dtduT[c*BL+bl] = {dt, dt*u} fp32 and szdT[c*BL+bl] = {hi: bf16(u*D*sz), lo: bf16(sz)}
__global__ __launch_bounds__(256) void dtprep(
        const float* __restrict__ proj, const float* __restrict__ W_dt,
        const float* __restrict__ b_dt, const unsigned short* __restrict__ ub,
        const unsigned short* __restrict__ szb, const float* __restrict__ Dp,
        float2* __restrict__ dtduT, unsigned int* __restrict__ szdT) {
    __shared__ alignas(16) unsigned char smem[64 * 65 * 8];   // 33280 B, multi-purpose
    float (*As)[68] = reinterpret_cast<float(*)[68]>(smem);           // 16x68x4 = 4352
    float (*Bs)[64] = reinterpret_cast<float(*)[64]>(smem + 4352);    // 16x64x4 = 4096
    float2 (*T2)[65] = reinterpret_cast<float2(*)[65]>(smem);         // 64x65x8
    unsigned int (*TU)[65] = reinterpret_cast<unsigned int(*)[65]>(smem); // 64x65x4

    int tid = threadIdx.x;
    int n0 = blockIdx.x * 64;   // c tile
    int m0 = blockIdx.y * 64;   // bl tile
    int ar = tid >> 2, ak = (tid & 3) << 2;
    int kb = tid >> 4, bc = (tid & 15) << 2;
    int ty = tid >> 4, tx = tid & 15;

    float acc[4][4] = {};
#pragma unroll
    for (int k0 = 0; k0 < R_; k0 += 16) {
        float4 av = *(const float4*)&proj[(size_t)(m0 + ar) * 96 + k0 + ak];
        As[ak + 0][ar] = av.x; As[ak + 1][ar] = av.y;
        As[ak + 2][ar] = av.z; As[ak + 3][ar] = av.w;
        float4 bv = *(const float4*)&W_dt[(size_t)(k0 + kb) * DI_ + n0 + bc];
        Bs[kb][bc + 0] = bv.x; Bs[kb][bc + 1] = bv.y;
        Bs[kb][bc + 2] = bv.z; Bs[kb][bc + 3] = bv.w;
        __syncthreads();
#pragma unroll
        for (int kk = 0; kk < 16; ++kk) {
            float a[4], bb[4];
#pragma unroll
            for (int i = 0; i < 4; ++i) a[i] = As[kk][ty * 4 + i];
#pragma unroll
            for (int j = 0; j < 4; ++j) bb[j] = Bs[kk][tx * 4 + j];
#pragma unroll
            for (int i = 0; i < 4; ++i)
#pragma unroll
                for (int j = 0; j < 4; ++j)
                    acc[i][j] = fmaf(a[i], bb[j], acc[i][j]);
        }
        __syncthreads();
    }

    // epilogue regs
    float4 bd = *(const float4*)&b_dt[n0 + tx * 4];
    float4 dp4 = *(const float4*)&Dp[n0 + tx * 4];
    float bda[4] = {bd.x, bd.y, bd.z, bd.w};
    float dpa[4] = {dp4.x, dp4.y, dp4.z, dp4.w};
    float2 d2[4][4];
    unsigned int su[4][4];
#pragma unroll
    for (int i = 0; i < 4; ++i) {
        int bl = m0 + ty * 4 + i;
        ushort4 u4 = *(const ushort4*)&ub[(size_t)bl * DI_ + n0 + tx * 4];
        ushort4 s4 = *(const ushort4*)&szb[(size_t)bl * DI_ + n0 + tx * 4];
        unsigned short ua[4] = {u4.x, u4.y, u4.z, u4.w};
        unsigned short sa[4] = {s4.x, s4.y, s4.z, s4.w};
#pragma unroll
        for (int j = 0; j < 4; ++j) {
            float v = acc[i][j] + bda[j];
            float dtv = fmaxf(v, 0.f) + __logf(1.f + __expf(-fabsf(v)));
            float uu = bf2f(ua[j]);
            float szv = bf2f(sa[j]);
            d2[i][j] = make_float2(dtv, dtv * uu);
            su[i][j] = ((unsigned)f2bf(uu * dpa[j] * szv) << 16) | (unsigned)f2bf(szv);
        }
    }

    // pass 1: {dt, dtu} transpose through LDS
#pragma unroll
    for (int i = 0; i < 4; ++i)
#pragma unroll
        for (int j = 0; j < 4; ++j)
            T2[ty * 4 + i][tx * 4 + j] = d2[i][j];
    __syncthreads();
#pragma unroll
    for (int i = 0; i < 8; ++i) {
        int c_l = (tid >> 5) + i * 8;
#pragma unroll
        for (int jj = 0; jj < 2; ++jj) {
            int bl_l = (tid & 31) + jj * 32;
            dtduT[(size_t)(n0 + c_l) * BL_ + m0 + bl_l] = T2[bl_l][c_l];
        }
    }
    __syncthreads();

    // pass 2: szd transpose through LDS
#pragma unroll
    for (int i = 0; i < 4; ++i)
#pragma unroll
        for (int j = 0; j < 4; ++j)
            TU[ty * 4 + i][tx * 4 + j] = su[i][j];
    __syncthreads();
#pragma unroll
    for (int i = 0; i < 8; ++i) {
        int c_l = (tid >> 5) + i * 8;
#pragma unroll
        for (int jj = 0; jj < 2; ++jj) {
            int bl_l = (tid & 31) + jj * 32;
            szdT[(size_t)(n0 + c_l) * BL_ + m0 + bl_l] = TU[bl_l][c_l];
        }
    }
}

// ---------------- Scan v11: v8 exact (best measured: 47.4 us) ----------------
// 2 channels/block, 512 thr, 16 chunks x 64 l. dd staged in LDS (single HBM pass);
// B/C read n-contiguous from proj (16-lane broadcast, L2-resident). Staggered LDS.
__global__ __launch_bounds__(512, 8) void scan_v11(
        const float2* __restrict__ dtduT, const unsigned int* __restrict__ szdT,
        const float* __restrict__ proj, const float* __restrict__ A_log,
        unsigned short* __restrict__ yzT) {
    int bc = blockIdx.x;            // 0..2047
    int b = bc >> 10;
    int cp = bc & 1023;
    int t = threadIdx.x;            // 0..511
    int n = t & 15;
    int cs = (t >> 4) & 1;
    int chunk = t >> 5;             // 0..15, 64 l each
    int c = cp * 2 + cs;

    __shared__ float dd[2][2120];   // {dt,dtu} interleaved, il2 layout, 8-float cs stagger
    __shared__ float sA[16][32];
    __shared__ float sB[16][32];
    __shared__ float ps[2][1096];   // IDX4 layout, 8-float cs stagger

    {   // stage both channel streams, coalesced: 512 threads x 4 l (32 B each)
        int half = t >> 8;
        int tt = t & 255;
        int l = tt * 4;
        int cload = cp * 2 + half;
        const float4* g = (const float4*)(dtduT + (size_t)cload * BL_ + (size_t)b * L_ + l);
        int il2 = l + ((l >> 6) << 1);
        float* dst = &dd[half][il2 * 2];
        *(float4*)(dst + 0) = g[0];
        *(float4*)(dst + 4) = g[1];
    }
    __syncthreads();

    float A2 = -__expf(A_log[c * N_ + n]) * 1.4426950408889634f;  // fold log2(e)
    int lb = chunk * 64;
    const float* ddp = &dd[cs][(lb + ((lb >> 6) << 1)) * 2];
    const float* pB = proj + (size_t)b * L_ * 96 + R_ + n + (size_t)lb * 96;
    const float* pC = pB + N_;

    // Phase 1: chunk-local scan over 64 l
    float a = 1.f, acc = 0.f;
#pragma unroll
    for (int q = 0; q < 16; ++q) {
        float4 d0 = *(const float4*)(ddp + q * 8);
        float4 d1 = *(const float4*)(ddp + q * 8 + 4);
        float b0 = pB[(q*4 + 0) * 96];
        float b1 = pB[(q*4 + 1) * 96];
        float b2 = pB[(q*4 + 2) * 96];
        float b3 = pB[(q*4 + 3) * 96];
        float e;
        e = fexp2(d0.x * A2); a *= e; acc = fmaf(e, acc, d0.y * b0);
        e = fexp2(d0.z * A2); a *= e; acc = fmaf(e, acc, d0.w * b1);
        e = fexp2(d1.x * A2); a *= e; acc = fmaf(e, acc, d1.y * b2);
        e = fexp2(d1.z * A2); a *= e; acc = fmaf(e, acc, d1.w * b3);
    }
    sA[chunk][cs * 16 + n] = a;
    sB[chunk][cs * 16 + n] = acc;
    __syncthreads();

    // Phase 2: serial combine across 16 chunks (32 threads: one per (cs,n))
    if (t < 32) {
        float hc = 0.f;
#pragma unroll
        for (int j = 0; j < 16; ++j) {
            float aj = sA[j][t];
            float bj = sB[j][t];
            sB[j][t] = hc;
            hc = fmaf(aj, hc, bj);
        }
    }
    __syncthreads();
    float h = sB[chunk][cs * 16 + n];

    // Phase 3: re-walk; DPP row-sum -> lane n==15 of each 16-lane group
    float* psb = &ps[cs][IDX4(lb)];
#pragma unroll
    for (int q = 0; q < 16; ++q) {
        float4 d0 = *(const float4*)(ddp + q * 8);
        float4 d1 = *(const float4*)(ddp + q * 8 + 4);
        float b0 = pB[(q*4 + 0) * 96], c0 = pC[(q*4 + 0) * 96];
        float b1 = pB[(q*4 + 1) * 96], c1 = pC[(q*4 + 1) * 96];
        float b2 = pB[(q*4 + 2) * 96], c2 = pC[(q*4 + 2) * 96];
        float b3 = pB[(q*4 + 3) * 96], c3 = pC[(q*4 + 3) * 96];
        float e, p0, p1, p2, p3;
        e = fexp2(d0.x * A2); h = fmaf(e, h, d0.y * b0); p0 = row16_sum(h * c0);
        e = fexp2(d0.z * A2); h = fmaf(e, h, d0.w * b1); p1 = row16_sum(h * c1);
        e = fexp2(d1.x * A2); h = fmaf(e, h, d1.y * b2); p2 = row16_sum(h * c2);
        e = fexp2(d1.z * A2); h = fmaf(e, h, d1.w * b3); p3 = row16_sum(h * c3);
        if (n == 15) *(float4*)&psb[q * 4] = (float4){p0, p1, p2, p3};
    }
    __syncthreads();

    // Epilogue: y = p * sz + u*D*sz, 4 per thread, coalesced (256 threads per channel)
    {
        int half = t >> 8;
        int tt = t & 255;
        int l = tt * 4;
        int c_out = cp * 2 + half;
        size_t tb = (size_t)c_out * BL_ + (size_t)b * L_;
        const float* pp = &ps[half][IDX4(l)];
        float4 p4 = *(const float4*)pp;
        uint4 sd4 = *(const uint4*)(szdT + tb + l);
        ushort4 o;
        o.x = f2bf(p4.x * bf2f((unsigned short)(sd4.x & 0xffff)) + bf2f((unsigned short)(sd4.x >> 16)));
        o.y = f2bf(p4.y * bf2f((unsigned short)(sd4.y & 0xffff)) + bf2f((unsigned short)(sd4.y >> 16)));
        o.z = f2bf(p4.z * bf2f((unsigned short)(sd4.z & 0xffff)) + bf2f((unsigned short)(sd4.z >> 16)));
        o.w = f2bf(p4.w * bf2f((unsigned short)(sd4.w & 0xffff)) + bf2f((unsigned short)(sd4.w >> 16)));
        *(ushort4*)(yzT + tb + l) = o;
    }
}

// ---------------- Transpose back: yzT (DI x BL) -> yzb (BL x DI) ----------------
__global__ void transpose_y(const unsigned short* __restrict__ yzT, unsigned short* __restrict__ yz) {
    __shared__ unsigned short t[32][33];
    int c0 = blockIdx.y * 32, bl0 = blockIdx.x * 32;
    int r = threadIdx.x >> 5;
    int col = threadIdx.x & 31;
#pragma unroll
    for (int i = 0; i < 4; ++i)
        t[r + i*8][col] = yzT[(size_t)(c0 + r + i*8) * BL_ + bl0 + col];
    __syncthreads();
#pragma unroll
    for (int i = 0; i < 4; ++i)
        yz[(size_t)(bl0 + r + i*8) * DI_ + c0 + col] = t[col][r + i*8];
}

extern "C" void kernel_launch(void* const* d_in, const int* in_sizes, int n_in,
                              void* d_out, int out_size, void* d_ws, size_t ws_size,
                              hipStream_t stream) {
    const float* x       = (const float*)d_in[0];
    const float* ln_w    = (const float*)d_in[1];
    const float* ln_b    = (const float*)d_in[2];
    const float* W_in    = (const float*)d_in[3];
    const float* conv_w  = (const float*)d_in[4];
    const float* conv_b  = (const float*)d_in[5];
    const float* W_x     = (const float*)d_in[6];
    const float* W_dt    = (const float*)d_in[7];
    const float* b_dt    = (const float*)d_in[8];
    const float* A_log   = (const float*)d_in[9];
    const float* D_param = (const float*)d_in[10];
    const float* W_out   = (const float*)d_in[11];
    float* out = (float*)d_out;

    uint8_t* p = (uint8_t*)d_ws;
    unsigned short* hb    = (unsigned short*)p;  p += (size_t)BL_ * D_ * 2;          // 4 MB  (dead after GEMM2)
    unsigned short* WinT  = (unsigned short*)p;  p += (size_t)4096 * 1024 * 2;       // 8 MB  (dead after GEMM2)
    float*          xib   = (float*)p;           p += (size_t)BL_ * DI_ * 4;         // 16 MB
    unsigned short* szb   = (unsigned short*)p;  p += (size_t)BL_ * DI_ * 2;         // 8 MB
    unsigned short* ub    = (unsigned short*)p;  p += (size_t)BL_ * DI_ * 2;         // 8 MB
    unsigned short* WxT   = (unsigned short*)p;  p += (size_t)96 * DI_ * 2;          // 0.375 MB
    float*          proj  = (float*)p;           p += (size_t)BL_ * 96 * 4;          // 0.75 MB
    unsigned short* WoutT = (unsigned short*)p;  p += (size_t)1024 * DI_ * 2;        // 4 MB
    float2*         dtduT = (float2*)p;          p += (size_t)BL_ * DI_ * 8;         // 32 MB
    unsigned int*   szdT  = (unsigned int*)p;    p += (size_t)BL_ * DI_ * 4;         // 16 MB
    unsigned short* yzT   = (unsigned short*)p;  p += (size_t)BL_ * DI_ * 2;         // 8 MB
    // projp (12 MB) aliases the dead hb+WinT region [0, 12MB): hb/WinT dead after GEMM2;
    // projp written by GEMM4 (MODE 4), read by reduce_proj; dead before transpose_y writes yzb.
    float*          projp = (float*)d_ws;
    // yzb aliases the dead hb+WinT region (8 MB <= 12 MB; written after projp is dead)
    unsigned short* yzb   = (unsigned short*)d_ws;

    hipMemcpyAsync(out, x, (size_t)BL_ * D_ * 4, hipMemcpyDeviceToDevice, stream);

    // weight transposes (one dispatch)
    transpose_cast_all<<<6336, 256, 0, stream>>>(W_in, W_x, W_out, WinT, WxT, WoutT);

    // 1. LayerNorm -> bf16
    ln_kernel<<<BL_, 256, 0, stream>>>(x, ln_w, ln_b, hb);

    // 2. xz = h @ W_in  (MFMA 128x64 tiles -> 1024 blocks, 4/CU)
    mfma_gemm_bt<128, 64, 3><<<dim3(4096 / 64, BL_ / 128, 1), 256, 0, stream>>>(
        hb, 1024, WinT, 1024, nullptr, 0, 1024, xib, szb);

    // 3. u = silu(conv(xi)) -> bf16  (4 channels/thread, float4)
    conv_silu_kernel<<<(BL_ * DI_) / 1024, 256, 0, stream>>>(xib, conv_w, conv_b, ub);

    // 4. projp[z] = u @ W_x (z-th K-slice)  (MFMA 64x96 tiles, split-K=16, plain stores -> 512 blocks)
    mfma_gemm_bt<64, 96, 4><<<dim3(1, BL_ / 64, 16), 256, 0, stream>>>(
        ub, DI_, WxT, DI_, projp, 96, 128, nullptr, nullptr);

    // 4b. proj = sum_z projp[z]
    reduce_proj<<<(BL_ * 24) / 256, 256, 0, stream>>>(projp, proj);

    // 5. fused dt-GEMM + softplus + pack + transpose
    dtprep<<<dim3(DI_ / 64, BL_ / 64), 256, 0, stream>>>(
        proj, W_dt, b_dt, ub, szb, D_param, dtduT, szdT);

    // 6. scan v11 (= v8, best measured) -> yzT
    scan_v11<<<B_ * DI_ / 2, 512, 0, stream>>>(dtduT, szdT, proj, A_log, yzT);

    // 6b. yzT -> row-major yzb
    transpose_y<<<dim3(BL_ / 32, DI_ / 32), 256, 0, stream>>>(yzT, yzb);

    // 7. out += yz @ W_out  (MFMA 128x64 tiles, split-K=4 atomic -> 1024 blocks, 4/CU)
    mfma_gemm_bt<128, 64, 1><<<dim3(1024 / 64, BL_ / 128, 4), 256, 0, stream>>>(
        yzb, DI_, WoutT, DI_, out, 1024, 512, nullptr, nullptr);
}